// Round 13
// baseline (135.547 us; speedup 1.0000x reference)
//
#include <hip/hip_runtime.h>

// Fused SNN forward for MI355X (gfx950) — round 13: phase-split + MFMA.
// Evidence r5-r12: duration*VALUBusy ~ 81-115us in EVERY config (VALU pipe
// saturated), MfmaUtil == 0 always. The FC matvec + reduce tree (~40% of
// loop VALU) is matmul-shaped -> move it to the idle matrix pipe.
//   Phase 1: pure LIF (no FC/reduce/exchange), counts -> LDS in MFMA
//            A-fragment layout as bf16 (exact for 0..4). ~96 ops/t, ~62
//            live regs (no fc weights in registers at all).
//   Phase 2: wave 0 does C[16t x 16o] += A[16t x 1376k] * B[k x o] via
//            43 K-steps of mfma_f32_16x16x32_bf16, 4 exact-bf16-split
//            weight passes (4x8 >= 24 mantissa bits -> every product
//            exact; result = reorder of exact fp32 products, the error
//            class that has measured absmax 0.0 for 12 rounds).
//   B-fragments prebuilt in d_ws (176KB, L2-resident) by a pre-kernel.
// A-frag layout (lane l): A[m=l&15][k=(l>>4)*8+jj], jj=0..7 contiguous.
// B-frag layout (lane l): B[k=(l>>4)*8+jj][n=l&15].
// C/D layout (verified, m89): row m = (l>>4)*4+reg, col n = l&15.

typedef float v2f __attribute__((ext_vector_type(2)));
typedef float f32x4 __attribute__((ext_vector_type(4)));
typedef short s16x8 __attribute__((ext_vector_type(8)));

#if __has_builtin(__builtin_elementwise_fma)
#define VFMA(a, b, c) __builtin_elementwise_fma((a), (b), (c))
#else
#define VFMA(a, b, c) ((a) * (b) + (c))
#endif

#define NU 6        // units per thread (256*6 = 1536 >= 1376)
#define KS 43       // K-blocks of 32: 43*32 = 1376 >= 1352
#define SPLITS 4    // exact bf16 decomposition of fp32 weights

__device__ __forceinline__ unsigned short bf16_rne(float f) {
    unsigned u = __float_as_uint(f);
    return (unsigned short)((u + 0x7FFFu + ((u >> 16) & 1u)) >> 16);
}
__device__ __forceinline__ float bf16_back(unsigned short h) {
    return __uint_as_float(((unsigned)h) << 16);
}

// ---- pre-kernel: build B fragments (4-way exact bf16 split of 0.25*fc_w)
// grid: SPLITS*KS blocks x 64 threads; thread (blk,l) emits one 16B frag.
__global__ void build_bfrag_kernel(const float* __restrict__ fc_w,
                                   s16x8* __restrict__ wsfrag) {
    const int blk = blockIdx.x;          // p*KS + ks
    const int p   = blk / KS;
    const int ks  = blk - p * KS;
    const int l   = threadIdx.x;         // 0..63
    s16x8 frag;
    #pragma unroll
    for (int jj = 0; jj < 8; ++jj) {
        const int k = ks * 32 + (l >> 4) * 8 + jj;
        const int n = l & 15;
        float r = (k < 1352 && n < 10) ? 0.25f * fc_w[n * 1352 + k] : 0.0f;
        unsigned short b = 0;
        for (int q = 0; q <= p; ++q) {   // p-th split term
            b = bf16_rne(r);
            r -= bf16_back(b);
        }
        frag[jj] = (short)b;
    }
    wsfrag[blk * 64 + l] = frag;
}

__global__ __launch_bounds__(256, 3) void snn_fused_kernel(
    const float* __restrict__ x,        // [4096, 1, 28, 28]
    const float* __restrict__ conv_w,   // [8, 1, 3, 3]
    const s16x8* __restrict__ wsfrag,   // [SPLITS*KS*64] B fragments
    float* __restrict__ out)            // [4096, 10]
{
    const int b    = blockIdx.x;
    const int tid  = threadIdx.x;
    const int lane = tid & 63;
    const int wid  = tid >> 6;          // 0..3

    // counts matrix in A-fragment order:
    // short index(u,t) = ks(u)*544 + s(u)*136 + t*8 + jj(u),
    //   ks = u>>5, s = (u&31)>>3, jj = u&7.  (quarter stride 136 shorts =
    //   272B: +1 dword mod 32 per quarter -> conflict-light b128 reads)
    __shared__ unsigned short sA[KS * 544];   // 46.75 KB
    __shared__ float scw[72];                 // conv weights
    __shared__ float scur2[160];              // [t][o]

    if (tid < 72) scw[tid] = conv_w[tid];

    // ---- per-thread unit geometry ----
    int xbase[NU], kbase[NU], sbase[NU];
    #pragma unroll
    for (int i = 0; i < NU; ++i) {
        const int u      = tid + 256 * i;
        const bool valid = (u < 1352);
        const int uu  = valid ? u : 0;
        const int k   = uu / 169;           // channel
        const int rem = uu - k * 169;
        const int pr  = rem / 13;           // pool row
        const int pc  = rem - pr * 13;      // pool col
        xbase[i] = 56 * pr + 2 * pc;
        kbase[i] = 9 * k;
        const int uo = u & 31;
        sbase[i] = (u >> 5) * 544 + (uo >> 3) * 136 + (uo & 7);
    }
    __syncthreads();                        // scw ready

    // ---- conv straight from global (3KB image, L2/L3-resident) ----
    const float* xb = x + (size_t)b * 784;
    v2f cur2[NU][2];   // conv out [unit][{cells01, cells23}]
    v2f mem2[NU][2];   // LIF-1 membranes
    #pragma unroll
    for (int i = 0; i < NU; ++i) {
        float cw[9];
        #pragma unroll
        for (int qq = 0; qq < 9; ++qq) cw[qq] = scw[kbase[i] + qq];

        float xr[4][4];
        #pragma unroll
        for (int r = 0; r < 4; ++r) {
            const float2* rp = reinterpret_cast<const float2*>(xb + xbase[i] + 28 * r);
            const float2 a = rp[0], c2 = rp[1];
            xr[r][0] = a.x; xr[r][1] = a.y; xr[r][2] = c2.x; xr[r][3] = c2.y;
        }

        const bool valid = (tid + 256 * i) < 1352;
        float cell[2][2];
        #pragma unroll
        for (int dr = 0; dr < 2; ++dr)
            #pragma unroll
            for (int dc = 0; dc < 2; ++dc) {
                float acc = 0.0f;
                #pragma unroll
                for (int ki = 0; ki < 3; ++ki)
                    #pragma unroll
                    for (int kj = 0; kj < 3; ++kj)
                        acc += xr[dr + ki][dc + kj] * cw[ki * 3 + kj];
                cell[dr][dc] = valid ? acc : 0.0f;
            }
        cur2[i][0] = (v2f){cell[0][0], cell[0][1]};
        cur2[i][1] = (v2f){cell[1][0], cell[1][1]};
        mem2[i][0] = (v2f){0.0f, 0.0f};
        mem2[i][1] = (v2f){0.0f, 0.0f};
    }

    const v2f half2 = (v2f){0.5f, 0.5f};

    // ---- phase 1: 16 timesteps of pure LIF; counts -> sA as bf16 ----
    #pragma unroll
    for (int t = 0; t < 16; ++t) {
        #pragma unroll
        for (int i = 0; i < NU; ++i) {
            v2f m01 = VFMA(half2, mem2[i][0], cur2[i][0]);
            v2f m23 = VFMA(half2, mem2[i][1], cur2[i][1]);
            v2f sp01, sp23;
            sp01.x = m01.x > 1.0f ? 1.0f : 0.0f;    // spike iff m > THR
            sp01.y = m01.y > 1.0f ? 1.0f : 0.0f;
            sp23.x = m23.x > 1.0f ? 1.0f : 0.0f;
            sp23.y = m23.y > 1.0f ? 1.0f : 0.0f;
            mem2[i][0] = m01 - sp01;                // subtract-reset (bit-identical)
            mem2[i][1] = m23 - sp23;
            v2f s = sp01 + sp23;
            const float c = s.x + s.y;              // 0..4 exact
            // exact bf16 of small int: truncate low mantissa (all zero)
            const unsigned short cb = (unsigned short)(__float_as_uint(c) >> 16);
            if (i < 5 || tid < 96)                  // u < 1376 only
                sA[sbase[i] + t * 8] = cb;
        }
    }
    __syncthreads();                                // counts complete

    // ---- phase 2: wave 0 does the [16 x 1376] x [1376 x 16] matmul ----
    if (wid == 0) {
        f32x4 acc[SPLITS];
        #pragma unroll
        for (int p = 0; p < SPLITS; ++p) acc[p] = (f32x4){0.f, 0.f, 0.f, 0.f};

        const int arow = (lane >> 4) * 136 + (lane & 15) * 8;
        for (int ks = 0; ks < KS; ++ks) {
            const s16x8 a = *reinterpret_cast<const s16x8*>(&sA[ks * 544 + arow]);
            #pragma unroll
            for (int p = 0; p < SPLITS; ++p) {      // 4 independent acc chains
                const s16x8 bw = wsfrag[(p * KS + ks) * 64 + lane];
                acc[p] = __builtin_amdgcn_mfma_f32_16x16x32_bf16(a, bw, acc[p], 0, 0, 0);
            }
        }
        const f32x4 csum = (acc[0] + acc[1]) + (acc[2] + acc[3]);
        const int o = lane & 15;
        if (o < 10) {
            #pragma unroll
            for (int r = 0; r < 4; ++r) {
                const int t = (lane >> 4) * 4 + r;  // C row = (l>>4)*4+reg
                scur2[t * 10 + o] = csum[r];
            }
        }
    }
    __syncthreads();                                // scur2 ready

    // ---- LIF-2 scan, 10 lanes ----
    if (tid < 10) {
        float m2 = 0.0f, cnt = 0.0f;
        #pragma unroll
        for (int t = 0; t < 16; ++t) {
            m2 = __builtin_fmaf(0.5f, m2, scur2[t * 10 + tid]);
            float ms = m2 - 1.0f;
            bool  sp = ms > 0.0f;
            m2  = sp ? ms : m2;
            cnt += sp ? 1.0f : 0.0f;
        }
        out[(size_t)b * 10 + tid] = cnt;
    }
}

extern "C" void kernel_launch(void* const* d_in, const int* in_sizes, int n_in,
                              void* d_out, int out_size, void* d_ws, size_t ws_size,
                              hipStream_t stream) {
    const float* x      = (const float*)d_in[0];  // 4096*784
    const float* conv_w = (const float*)d_in[1];  // 72
    const float* fc_w   = (const float*)d_in[2];  // 13520
    float* out          = (float*)d_out;          // 40960
    s16x8* wsfrag       = (s16x8*)d_ws;           // needs 176128 B

    // build B fragments (4-split bf16 weights), then the fused SNN kernel
    build_bfrag_kernel<<<SPLITS * KS, 64, 0, stream>>>(fc_w, wsfrag);

    const int B = in_sizes[0] / 784;              // 4096
    snn_fused_kernel<<<B, 256, 0, stream>>>(x, conv_w, wsfrag, out);
}

// Round 14
// 76.344 us; speedup vs baseline: 1.7755x; 1.7755x over previous
//
#include <hip/hip_runtime.h>

// Fused SNN forward for MI355X (gfx950) — round 14.
// r13 + WAVE-PARALLEL phase 2: wave p computes weight-split p (SPLITS=4 maps
// 1:1 onto the 4 waves). r13 ran phase 2 on one wave (3 idle at barrier) with
// 4 dependent L2 loads/iter -> ~60% of wall was waiting (VALUBusy 34,
// MfmaUtil 3.2 = 4.5us real MFMA). Now each wave: 43 x {1 global load +
// 1 ds_read_b128 + 1 MFMA}, loads independent across iters and waves.
// Partial C per wave -> scC; final reduce sums splits pairwise (same order
// as r13 -> bit-identical). Phase 1 / conv / layouts / pre-kernel unchanged.

typedef float v2f __attribute__((ext_vector_type(2)));
typedef float f32x4 __attribute__((ext_vector_type(4)));
typedef short s16x8 __attribute__((ext_vector_type(8)));

#if __has_builtin(__builtin_elementwise_fma)
#define VFMA(a, b, c) __builtin_elementwise_fma((a), (b), (c))
#else
#define VFMA(a, b, c) ((a) * (b) + (c))
#endif

#define NU 6        // units per thread (256*6 = 1536 >= 1376)
#define KS 43       // K-blocks of 32: 43*32 = 1376 >= 1352
#define SPLITS 4    // exact bf16 decomposition of fp32 weights (== waves)

__device__ __forceinline__ unsigned short bf16_rne(float f) {
    unsigned u = __float_as_uint(f);
    return (unsigned short)((u + 0x7FFFu + ((u >> 16) & 1u)) >> 16);
}
__device__ __forceinline__ float bf16_back(unsigned short h) {
    return __uint_as_float(((unsigned)h) << 16);
}

// ---- pre-kernel: build B fragments (4-way exact bf16 split of 0.25*fc_w)
__global__ void build_bfrag_kernel(const float* __restrict__ fc_w,
                                   s16x8* __restrict__ wsfrag) {
    const int blk = blockIdx.x;          // p*KS + ks
    const int p   = blk / KS;
    const int ks  = blk - p * KS;
    const int l   = threadIdx.x;         // 0..63
    s16x8 frag;
    #pragma unroll
    for (int jj = 0; jj < 8; ++jj) {
        const int k = ks * 32 + (l >> 4) * 8 + jj;
        const int n = l & 15;
        float r = (k < 1352 && n < 10) ? 0.25f * fc_w[n * 1352 + k] : 0.0f;
        unsigned short b = 0;
        for (int q = 0; q <= p; ++q) {   // p-th split term
            b = bf16_rne(r);
            r -= bf16_back(b);
        }
        frag[jj] = (short)b;
    }
    wsfrag[blk * 64 + l] = frag;
}

__global__ __launch_bounds__(256, 3) void snn_fused_kernel(
    const float* __restrict__ x,        // [4096, 1, 28, 28]
    const float* __restrict__ conv_w,   // [8, 1, 3, 3]
    const s16x8* __restrict__ wsfrag,   // [SPLITS*KS*64] B fragments
    float* __restrict__ out)            // [4096, 10]
{
    const int b    = blockIdx.x;
    const int tid  = threadIdx.x;
    const int lane = tid & 63;
    const int wid  = tid >> 6;          // 0..3

    // counts matrix in A-fragment order:
    // short index(u,t) = (u>>5)*544 + ((u&31)>>3)*136 + t*8 + (u&7)
    __shared__ unsigned short sA[KS * 544];   // 46.75 KB
    __shared__ float scC[4 * 256];            // per-wave partial C [w][t*16+o]
    __shared__ float scw[72];                 // conv weights
    __shared__ float scur2[160];              // [t][o]

    if (tid < 72) scw[tid] = conv_w[tid];

    // ---- per-thread unit geometry ----
    int xbase[NU], kbase[NU], sbase[NU];
    #pragma unroll
    for (int i = 0; i < NU; ++i) {
        const int u      = tid + 256 * i;
        const bool valid = (u < 1352);
        const int uu  = valid ? u : 0;
        const int k   = uu / 169;           // channel
        const int rem = uu - k * 169;
        const int pr  = rem / 13;           // pool row
        const int pc  = rem - pr * 13;      // pool col
        xbase[i] = 56 * pr + 2 * pc;
        kbase[i] = 9 * k;
        const int uo = u & 31;
        sbase[i] = (u >> 5) * 544 + (uo >> 3) * 136 + (uo & 7);
    }
    __syncthreads();                        // scw ready

    // ---- conv straight from global (3KB image, L2/L3-resident) ----
    const float* xb = x + (size_t)b * 784;
    v2f cur2[NU][2];   // conv out [unit][{cells01, cells23}]
    v2f mem2[NU][2];   // LIF-1 membranes
    #pragma unroll
    for (int i = 0; i < NU; ++i) {
        float cw[9];
        #pragma unroll
        for (int qq = 0; qq < 9; ++qq) cw[qq] = scw[kbase[i] + qq];

        float xr[4][4];
        #pragma unroll
        for (int r = 0; r < 4; ++r) {
            const float2* rp = reinterpret_cast<const float2*>(xb + xbase[i] + 28 * r);
            const float2 a = rp[0], c2 = rp[1];
            xr[r][0] = a.x; xr[r][1] = a.y; xr[r][2] = c2.x; xr[r][3] = c2.y;
        }

        const bool valid = (tid + 256 * i) < 1352;
        float cell[2][2];
        #pragma unroll
        for (int dr = 0; dr < 2; ++dr)
            #pragma unroll
            for (int dc = 0; dc < 2; ++dc) {
                float acc = 0.0f;
                #pragma unroll
                for (int ki = 0; ki < 3; ++ki)
                    #pragma unroll
                    for (int kj = 0; kj < 3; ++kj)
                        acc += xr[dr + ki][dc + kj] * cw[ki * 3 + kj];
                cell[dr][dc] = valid ? acc : 0.0f;
            }
        cur2[i][0] = (v2f){cell[0][0], cell[0][1]};
        cur2[i][1] = (v2f){cell[1][0], cell[1][1]};
        mem2[i][0] = (v2f){0.0f, 0.0f};
        mem2[i][1] = (v2f){0.0f, 0.0f};
    }

    const v2f half2 = (v2f){0.5f, 0.5f};

    // ---- phase 1: 16 timesteps of pure LIF; counts -> sA as bf16 ----
    #pragma unroll
    for (int t = 0; t < 16; ++t) {
        #pragma unroll
        for (int i = 0; i < NU; ++i) {
            v2f m01 = VFMA(half2, mem2[i][0], cur2[i][0]);
            v2f m23 = VFMA(half2, mem2[i][1], cur2[i][1]);
            v2f sp01, sp23;
            sp01.x = m01.x > 1.0f ? 1.0f : 0.0f;    // spike iff m > THR
            sp01.y = m01.y > 1.0f ? 1.0f : 0.0f;
            sp23.x = m23.x > 1.0f ? 1.0f : 0.0f;
            sp23.y = m23.y > 1.0f ? 1.0f : 0.0f;
            mem2[i][0] = m01 - sp01;                // subtract-reset (bit-identical)
            mem2[i][1] = m23 - sp23;
            v2f s = sp01 + sp23;
            const float c = s.x + s.y;              // 0..4 exact
            const unsigned short cb = (unsigned short)(__float_as_uint(c) >> 16);
            if (i < 5 || tid < 96)                  // u < 1376 only
                sA[sbase[i] + t * 8] = cb;
        }
    }
    __syncthreads();                                // counts complete

    // ---- phase 2: wave p computes split p of the [16x1376]x[1376x16] ----
    {
        const int p = wid;                          // split index == wave id
        f32x4 acc = (f32x4){0.f, 0.f, 0.f, 0.f};
        const int arow = (lane >> 4) * 136 + (lane & 15) * 8;
        #pragma unroll 2
        for (int ks = 0; ks < KS; ++ks) {
            const s16x8 a  = *reinterpret_cast<const s16x8*>(&sA[ks * 544 + arow]);
            const s16x8 bw = wsfrag[(p * KS + ks) * 64 + lane];
            acc = __builtin_amdgcn_mfma_f32_16x16x32_bf16(a, bw, acc, 0, 0, 0);
        }
        // store partial C: row t = (l>>4)*4 + r, col o = l&15 (verified layout)
        const int o = lane & 15;
        #pragma unroll
        for (int r = 0; r < 4; ++r) {
            const int t = (lane >> 4) * 4 + r;
            scC[wid * 256 + t * 16 + o] = acc[r];
        }
    }
    __syncthreads();                                // partials ready

    // ---- combine splits (same pairwise order as r13) + LIF-2 scan ----
    if (tid < 160) {
        const int t = tid / 10;
        const int o = tid - t * 10;
        const int idx = t * 16 + o;
        scur2[tid] = (scC[idx] + scC[256 + idx]) + (scC[512 + idx] + scC[768 + idx]);
    }
    __syncthreads();                                // scur2 ready

    if (tid < 10) {
        float m2 = 0.0f, cnt = 0.0f;
        #pragma unroll
        for (int t = 0; t < 16; ++t) {
            m2 = __builtin_fmaf(0.5f, m2, scur2[t * 10 + tid]);
            float ms = m2 - 1.0f;
            bool  sp = ms > 0.0f;
            m2  = sp ? ms : m2;
            cnt += sp ? 1.0f : 0.0f;
        }
        out[(size_t)b * 10 + tid] = cnt;
    }
}

extern "C" void kernel_launch(void* const* d_in, const int* in_sizes, int n_in,
                              void* d_out, int out_size, void* d_ws, size_t ws_size,
                              hipStream_t stream) {
    const float* x      = (const float*)d_in[0];  // 4096*784
    const float* conv_w = (const float*)d_in[1];  // 72
    const float* fc_w   = (const float*)d_in[2];  // 13520
    float* out          = (float*)d_out;          // 40960
    s16x8* wsfrag       = (s16x8*)d_ws;           // needs 176128 B

    build_bfrag_kernel<<<SPLITS * KS, 64, 0, stream>>>(fc_w, wsfrag);

    const int B = in_sizes[0] / 784;              // 4096
    snn_fused_kernel<<<B, 256, 0, stream>>>(x, conv_w, wsfrag, out);
}